// Round 1
// baseline (419.404 us; speedup 1.0000x reference)
//
#include <hip/hip_runtime.h>

typedef _Float16 f16x8 __attribute__((ext_vector_type(8)));
typedef _Float16 f16x4 __attribute__((ext_vector_type(4)));
typedef _Float16 f16x2 __attribute__((ext_vector_type(2)));
typedef float f32x4 __attribute__((ext_vector_type(4)));
typedef float f32x2 __attribute__((ext_vector_type(2)));

#define GLD_LDS16(gp, lp)                                                        \
  __builtin_amdgcn_global_load_lds(                                              \
      (const __attribute__((address_space(1))) void*)(gp),                       \
      (__attribute__((address_space(3))) void*)(lp), 16, 0, 0)

// ---------------- kernel 0: weights -> f16 (Cw = A - B, Bw = B) ----------------
// G*H*H = 4*512*512 = 1,048,576 floats each; 1024 blocks x 256 thr x 4 floats.
__global__ void prep_weights_k(const float* __restrict__ A, const float* __restrict__ B,
                               _Float16* __restrict__ Cw, _Float16* __restrict__ Bw) {
  int gid = blockIdx.x * 256 + threadIdx.x;
  f32x4 a = ((const f32x4*)A)[gid];
  f32x4 b = ((const f32x4*)B)[gid];
  f16x4 c, bb;
  c.x = (_Float16)(a.x - b.x); c.y = (_Float16)(a.y - b.y);
  c.z = (_Float16)(a.z - b.z); c.w = (_Float16)(a.w - b.w);
  bb.x = (_Float16)b.x; bb.y = (_Float16)b.y;
  bb.z = (_Float16)b.z; bb.w = (_Float16)b.w;
  ((f16x4*)Cw)[gid] = c;
  ((f16x4*)Bw)[gid] = bb;
}

// ---------------- kernel 1: x -> f16, S[b,h] = sum_i x[b,i,h] ----------------
// 4096 blocks (one per b) x 256 threads; each thread owns 2 consecutive h.
__global__ void prep_x_k(const float* __restrict__ x, _Float16* __restrict__ xh,
                         _Float16* __restrict__ Sh) {
  int b = blockIdx.x, t = threadIdx.x;
  const f32x2* xr = (const f32x2*)(x + (size_t)b * 4096);
  f16x2* xo = (f16x2*)xh + (size_t)b * 2048;
  float s0 = 0.f, s1 = 0.f;
#pragma unroll
  for (int i = 0; i < 8; ++i) {
    f32x2 v = xr[i * 256 + t];
    f16x2 h;
    h.x = (_Float16)v.x; h.y = (_Float16)v.y;
    xo[i * 256 + t] = h;
    s0 += v.x; s1 += v.y;
  }
  f16x2 sv;
  sv.x = (_Float16)s0; sv.y = (_Float16)s1;
  ((f16x2*)Sh)[(size_t)b * 256 + t] = sv;
}

// ---------------- GEMM: out = Am[M,512] @ W[2048,512]^T ----------------
// MODE 0: out = tvec buffer, plain row-major [M,2048] (t = S @ B^T)
// MODE 1: out[b*16384 + g*4096 + i*512 + h] = acc + tvec[b*2048 + col]
//         where row m = b*8+i, col = g*512+h
// 128x128 tile, BK=32, 4 waves (2x2 of 64x64), mfma_f32_16x16x32_f16.
// LDS tiles stored [row][k] with 16B chunks XOR-swizzled: phys = logical ^ ((row>>1)&3)
// -> ds_read_b128 per 16-lane group is 2-way bank aliased (free, m136).
template <int MODE>
__global__ __launch_bounds__(256) void gemm_k(const _Float16* __restrict__ Am,
                                              const _Float16* __restrict__ W,
                                              const float* __restrict__ tvec,
                                              float* __restrict__ out) {
  __shared__ __align__(16) _Float16 lA[128 * 32];
  __shared__ __align__(16) _Float16 lB[128 * 32];

  const int tid = threadIdx.x;
  const int lane = tid & 63;
  const int wv = tid >> 6;
  const int tile_n = blockIdx.x & 15;
  const int tile_m = blockIdx.x >> 4;

  // Staging: tile = 128 rows x 64B = 512 16B-chunks; chunk c = i*256 + tid.
  // global_load_lds writes LDS at (wave-uniform base) + lane*16, so chunk->LDS
  // is identity; we swizzle the *global* source k-chunk instead.
  const _Float16* gA[2];
  const _Float16* gB[2];
  _Float16* lpA[2];
  _Float16* lpB[2];
#pragma unroll
  for (int i = 0; i < 2; ++i) {
    int c = i * 256 + tid;
    int row = c >> 2;
    int lc = (c & 3) ^ ((row >> 1) & 3);
    gA[i] = Am + ((size_t)(tile_m * 128 + row) * 512 + lc * 8);
    gB[i] = W + ((size_t)(tile_n * 128 + row) * 512 + lc * 8);
    lpA[i] = &lA[(size_t)(i * 256 + wv * 64) * 8];
    lpB[i] = &lB[(size_t)(i * 256 + wv * 64) * 8];
  }

  const int lm = lane & 15;
  const int q = lane >> 4;
  const int mw = (wv >> 1) * 64;  // wave row origin in tile
  const int nw = (wv & 1) * 64;   // wave col origin in tile

  // A frag: lane holds A[m=lm][k=q*8+j]; B frag: lane holds B[k=q*8+j][n=lm]
  // (we store W rows [n][k] in lB, so same read pattern as A).
  int aoff[4], boff[4];
#pragma unroll
  for (int f = 0; f < 4; ++f) {
    int rA = mw + f * 16 + lm;
    aoff[f] = rA * 32 + (q ^ ((rA >> 1) & 3)) * 8;
    int rB = nw + f * 16 + lm;
    boff[f] = rB * 32 + (q ^ ((rB >> 1) & 3)) * 8;
  }

  f32x4 acc[4][4];
#pragma unroll
  for (int im = 0; im < 4; ++im)
#pragma unroll
    for (int in = 0; in < 4; ++in) acc[im][in] = (f32x4){0.f, 0.f, 0.f, 0.f};

  for (int kt = 0; kt < 16; ++kt) {
    __syncthreads();  // prior ds_reads drained before overwrite
#pragma unroll
    for (int i = 0; i < 2; ++i) {
      GLD_LDS16(gA[i] + kt * 32, lpA[i]);
      GLD_LDS16(gB[i] + kt * 32, lpB[i]);
    }
    __syncthreads();  // vmcnt(0) drain: staged data visible
    f16x8 af[4], bf[4];
#pragma unroll
    for (int f = 0; f < 4; ++f) {
      af[f] = *(const f16x8*)&lA[aoff[f]];
      bf[f] = *(const f16x8*)&lB[boff[f]];
    }
#pragma unroll
    for (int im = 0; im < 4; ++im)
#pragma unroll
      for (int in = 0; in < 4; ++in)
        acc[im][in] =
            __builtin_amdgcn_mfma_f32_16x16x32_f16(af[im], bf[in], acc[im][in], 0, 0, 0);
  }

  // Epilogue. C/D layout: col = lane&15, row = q*4 + reg (m89-verified).
  // mbase is 4-aligned with (mbase&7) in {0,4} -> all 4 regs share one b.
#pragma unroll
  for (int im = 0; im < 4; ++im) {
    const int mbase = tile_m * 128 + mw + im * 16 + q * 4;
#pragma unroll
    for (int in = 0; in < 4; ++in) {
      const int col = tile_n * 128 + nw + in * 16 + lm;
      f32x4 v = acc[im][in];
      if (MODE == 1) {
        const int b = mbase >> 3;
        const float tv = tvec[(size_t)b * 2048 + col];
        float* op = out + (size_t)b * 16384 + (size_t)(col >> 9) * 4096 +
                    (size_t)(mbase & 7) * 512 + (col & 511);
#pragma unroll
        for (int r = 0; r < 4; ++r) op[r * 512] = v[r] + tv;
      } else {
        float* op = out + (size_t)mbase * 2048 + col;
#pragma unroll
        for (int r = 0; r < 4; ++r) op[(size_t)r * 2048] = v[r];
      }
    }
  }
}

extern "C" void kernel_launch(void* const* d_in, const int* in_sizes, int n_in,
                              void* d_out, int out_size, void* d_ws, size_t ws_size,
                              hipStream_t stream) {
  const float* x = (const float*)d_in[0];  // [4096, 4096]
  const float* A = (const float*)d_in[1];  // [4, 512, 512]
  const float* B = (const float*)d_in[2];  // [4, 512, 512]
  float* out = (float*)d_out;              // [4096, 16384]
  char* ws = (char*)d_ws;

  // ws layout (bytes): xh f16[32768*512] @0 (32MB); Sh f16[4096*512] @32MB (4MB);
  // Cw f16[2048*512] @36MB (2MB); Bw f16[2048*512] @38MB (2MB); t f32[4096*2048] @40MB (32MB)
  _Float16* xh = (_Float16*)(ws);
  _Float16* Sh = (_Float16*)(ws + 33554432u);
  _Float16* Cw = (_Float16*)(ws + 37748736u);
  _Float16* Bw = (_Float16*)(ws + 39845888u);
  float* tv = (float*)(ws + 41943040u);

  prep_weights_k<<<1024, 256, 0, stream>>>(A, B, Cw, Bw);
  prep_x_k<<<4096, 256, 0, stream>>>(x, xh, Sh);
  // t[b, g*512+h] = sum_k S[b,k] * B[g,h,k] : M=4096 -> 32 m-tiles, 16 n-tiles
  gemm_k<0><<<512, 256, 0, stream>>>(Sh, Bw, nullptr, tv);
  // out = x @ (A-B)^T + t : M=32768 -> 256 m-tiles, 16 n-tiles
  gemm_k<1><<<4096, 256, 0, stream>>>(xh, Cw, tv, out);
}